// Round 16
// baseline (944.934 us; speedup 1.0000x reference)
//
#include <hip/hip_runtime.h>
#include <math.h>

#define B_ 16
#define L_ 720
#define C_ 128
#define H_ 96
#define F2_ 49
#define K_ 8
#define S_ 8
#define OUT_ 833          // F2*(2K+1)
#define SEQLEN 816        // L + H
#define NF 361            // rfft bins for L=720

__device__ __forceinline__ float2 cmulp(float2 a, float2 w) {   // a * w (complex)
  return make_float2(a.x*w.x - a.y*w.y, a.x*w.y + a.y*w.x);
}

// Per-wave LDS fence: all my LDS ops done, and no compiler reordering across it (rule #18).
#define WSYNC() do { asm volatile("s_waitcnt lgkmcnt(0)" ::: "memory"); __builtin_amdgcn_sched_barrier(0); } while (0)

// W5^m = e^{+2*pi*i*m/5}
__device__ __constant__ float W5X[5] = {1.f, 0.30901699437494742f, -0.80901699437494745f, -0.80901699437494745f, 0.30901699437494742f};
__device__ __constant__ float W5Y[5] = {0.f, 0.95105651629515357f, 0.58778525229247312f, -0.58778525229247312f, -0.95105651629515357f};

// DFT-8, positive exponent (omega = e^{+i*pi/4}) — verified in R9.
__device__ __forceinline__ void dft8_pos(const float2 zin[8], float2 X[8]) {
  const float RH = 0.70710678118654752440f;
  const float2 A0 = make_float2(zin[0].x+zin[4].x, zin[0].y+zin[4].y);
  const float2 A1 = make_float2(zin[0].x-zin[4].x, zin[0].y-zin[4].y);
  const float2 A2 = make_float2(zin[2].x+zin[6].x, zin[2].y+zin[6].y);
  const float2 A3 = make_float2(zin[2].x-zin[6].x, zin[2].y-zin[6].y);
  const float2 A4 = make_float2(zin[1].x+zin[5].x, zin[1].y+zin[5].y);
  const float2 A5 = make_float2(zin[1].x-zin[5].x, zin[1].y-zin[5].y);
  const float2 A6 = make_float2(zin[3].x+zin[7].x, zin[3].y+zin[7].y);
  const float2 A7 = make_float2(zin[3].x-zin[7].x, zin[3].y-zin[7].y);
  const float2 B0 = make_float2(A0.x+A2.x, A0.y+A2.y);
  const float2 B1 = make_float2(A0.x-A2.x, A0.y-A2.y);
  const float2 B2 = make_float2(A4.x+A6.x, A4.y+A6.y);
  const float2 B3 = make_float2(A4.x-A6.x, A4.y-A6.y);
  X[0] = make_float2(B0.x+B2.x, B0.y+B2.y);
  X[4] = make_float2(B0.x-B2.x, B0.y-B2.y);
  X[2] = make_float2(B1.x - B3.y, B1.y + B3.x);   // B1 + i*B3
  X[6] = make_float2(B1.x + B3.y, B1.y - B3.x);   // B1 - i*B3
  const float2 CI   = make_float2(-A3.y, A3.x);   // i*A3
  const float2 W1s1 = make_float2((A5.x - A5.y)*RH, (A5.x + A5.y)*RH);   // w^1*A5
  const float2 W3s1 = make_float2((-A5.x - A5.y)*RH, (A5.x - A5.y)*RH);  // w^3*A5
  const float2 W1s3 = make_float2((A7.x - A7.y)*RH, (A7.x + A7.y)*RH);   // w^1*A7
  const float2 W3s3 = make_float2((-A7.x - A7.y)*RH, (A7.x - A7.y)*RH);  // w^3*A7
  X[1] = make_float2(A1.x + CI.x + W1s1.x + W3s3.x, A1.y + CI.y + W1s1.y + W3s3.y);
  X[5] = make_float2(A1.x + CI.x - W1s1.x - W3s3.x, A1.y + CI.y - W1s1.y - W3s3.y);
  X[3] = make_float2(A1.x - CI.x + W3s1.x + W1s3.x, A1.y - CI.y + W3s1.y + W1s3.y);
  X[7] = make_float2(A1.x - CI.x - W3s1.x - W1s3.x, A1.y - CI.y - W3s1.y - W1s3.y);
}

// ---------------------------------------------------------------- K0: twiddle table (once per launch)
__global__ __launch_bounds__(256) void k0_tab(float2* __restrict__ wtab_g) {
  for (int k = threadIdx.x; k < L_; k += 256) {
    double ang = (double)k * 0.008726646259971647884;   // 2*pi/720
    wtab_g[k] = make_float2((float)cos(ang), (float)sin(ang));
  }
}

// ---------------------------------------------------------------- K1: normalize + forward rfft, 2 adjacent channels per block
__global__ __launch_bounds__(256) void k1_fused(const float* __restrict__ x,
                                                const float* __restrict__ yh,
                                                const float2* __restrict__ wtab_g,
                                                float* __restrict__ seq,
                                                float* __restrict__ mu_g,
                                                float* __restrict__ std_g,
                                                float2* __restrict__ Rc) {
  const int bc0 = blockIdx.x * 2;       // channels bc0, bc0+1 (adjacent c -> float2 loads)
  const int b = bc0 >> 7, c0 = bc0 & 127;
  const int tid = threadIdx.x;
  __shared__ float xrow[2][L_];
  __shared__ float yrow[2][H_];
  __shared__ float2 wt[L_];
  __shared__ float red[4];

  const float* xb = x + (size_t)b * L_ * C_ + c0;
  for (int l = tid; l < L_; l += 256) {
    const float2 v = *(const float2*)&xb[(size_t)l * C_];
    xrow[0][l] = v.x; xrow[1][l] = v.y;
  }
  const float* yb = yh + (size_t)b * H_ * C_ + c0;
  if (tid < H_) {
    const float2 v = *(const float2*)&yb[(size_t)tid * C_];
    yrow[0][tid] = v.x; yrow[1][tid] = v.y;
  }
  for (int k = tid; k < L_; k += 256) wt[k] = wtab_g[k];
  __syncthreads();

  for (int ch = 0; ch < 2; ++ch) {
    float s = 0.f;
    for (int l = tid; l < L_; l += 256) s += xrow[ch][l];
    for (int off = 32; off; off >>= 1) s += __shfl_down(s, off, 64);
    if ((tid & 63) == 0) red[tid >> 6] = s;
    __syncthreads();
    const float mu = (red[0] + red[1] + red[2] + red[3]) * (1.0f / L_);
    __syncthreads();
    float vs = 0.f;
    for (int l = tid; l < L_; l += 256) { float d = xrow[ch][l] - mu; vs += d * d; }
    for (int off = 32; off; off >>= 1) vs += __shfl_down(vs, off, 64);
    if ((tid & 63) == 0) red[tid >> 6] = vs;
    __syncthreads();
    const float stdv = sqrtf((red[0] + red[1] + red[2] + red[3]) * (1.0f / L_) + 1e-8f);
    const float inv = 1.0f / stdv;
    if (tid == 0) { mu_g[bc0 + ch] = mu; std_g[bc0 + ch] = stdv; }
    __syncthreads();                     // red reused next ch; also xrow rewrite guard
    float* sq = seq + (size_t)(bc0 + ch) * SEQLEN;
    for (int l = tid; l < L_; l += 256) { const float v = (xrow[ch][l] - mu) * inv; xrow[ch][l] = v; sq[l] = v; }
    if (tid < H_) sq[L_ + tid] = (yrow[ch][tid] - mu) * inv;
    __syncthreads();
  }

  for (int u = tid; u < 2 * NF; u += 256) {   // rfft (negative exponent), from normalized LDS rows
    const int row = u / NF, f = u - row * NF;
    float re = 0.f, im = 0.f;
    int m = 0;
    const float* xr = xrow[row];
    for (int l = 0; l < L_; ++l) {
      const float v = xr[l];
      const float2 w = wt[m];
      re = fmaf(v, w.x, re);
      im = fmaf(-v, w.y, im);
      m += f; if (m >= L_) m -= L_;
    }
    Rc[(size_t)(bc0 + row) * NF + f] = make_float2(re, im);
  }
}

// ---------------------------------------------------------------- K2: per-wave spectral product + real-packed 360-pt IFFT, 2 pairs/wave/iter
// cc (real, len 720) via z[n] = cc[2n] + i*cc[2n+1] = IDFT360(Z); Z from Hermitian P (see R9).
// R16: the persistent ~500 MB spill (R13/R14/R15) was stage-2's wave-uniform peak: dual-column
// lanes carried 20 accumulators + z[9] + in-flight LDS reads > the 84-reg cap. Fix: 72 (row,col)
// tasks over 64 lanes in 2 fenced passes (10 accumulators/chain) + scalar z/t9 loads.
// Stage-1 stays split through LDS (1a Z-build, 1b in-place DFT-8) — low pressure by design.
// __launch_bounds__(256,3): bound N => VGPR cap 256/N and ~N blocks/CU (R13: 3 blocks = best).
// Spill detector: WRITE_SIZE must be ~2 MB.
__global__ __launch_bounds__(256, 3) void k2_fft(const float2* __restrict__ Rc,
                                                 const float2* __restrict__ wtab_g,
                                                 float* __restrict__ r_arr,
                                                 int* __restrict__ t_arr) {
  // XCD-aware bijective swizzle (T1): grid = 9216 = 8 * 1152 -> each XCD gets 2 contiguous batches.
  const int phys = blockIdx.x;
  int idx = (phys & 7) * 1152 + (phys >> 3);
  const int b = idx / 576;
  idx -= b * 576;
  int g = 0;
  while (true) { const int cnt = (8 - g) << 4; if (idx < cnt) break; idx -= cnt; ++g; }
  const int rows = 8 - g;
  const int c1 = (g << 4) + idx / rows;
  const int c2t = g + idx % rows;
  const int c2base = c2t << 4;
  const int tid = threadIdx.x;
  const int wid = tid >> 6, lane = tid & 63;

  __shared__ float2 r1c[NF];
  __shared__ float2 t9[81];                      // W9^{a*c} at [9a+c]
  __shared__ float2 t45[45];                     // W45^{b*c} at [9b+c]
  __shared__ float2 Yw[4][2][360];               // per-wave, per-pair: Z then stage-1 out (in place)
  __shared__ __align__(16) float ccw[4][2][728]; // per-wave, per-pair cc row

  for (int f = tid; f < NF; f += 256) r1c[f] = Rc[((size_t)(b * C_ + c1)) * NF + f];
  for (int i = tid; i < 81; i += 256) { int a = i / 9, c = i % 9; t9[i] = wtab_g[80 * ((a * c) % 9)]; }
  for (int i = tid; i < 45; i += 256) { int bb = i / 9, c = i % 9; t45[i] = wtab_g[16 * bb * c]; }
  __syncthreads();                   // the only block-wide barrier

  const float SCALE = 1.0f / 518400.0f;   // 1/720^2

  for (int it = 0; it < 2; ++it) {
    const int c2A = c2base + (wid << 2) + 2 * it;    // pair A; pair B = c2A+1
    if (c2A + 1 < c1) continue;      // both pairs below diagonal: nothing would be emitted
    const float2* R2A = Rc + ((size_t)(b * C_ + c2A)) * NF;   // L2-hot after swizzle
    const float2* R2B = R2A + NF;

    // ---- stage 1a: Z build (both pairs) -> Yw. Tiny per-task register footprint, coalesced loads.
    for (int t = lane; t < 720; t += 64) {
      const int pr = (t >= 360) ? 1 : 0;
      const int k = t - 360 * pr;              // in [0, 360)
      const float2* R2 = pr ? R2B : R2A;
      const int fB = 360 - k;                  // in [1, 360]
      const float2 a1 = r1c[k];
      const float2 a2 = r1c[fB];
      const float2 b1 = R2[k];
      const float2 b2 = R2[fB];
      const float2 pA = make_float2(a1.x*b1.x + a1.y*b1.y, a1.y*b1.x - a1.x*b1.y);
      float2 pB = make_float2(a2.x*b2.x + a2.y*b2.y, a2.y*b2.x - a2.x*b2.y);
      pB.y = (k == 0) ? pB.y : -pB.y;          // conj for k>=1
      const float2 E = make_float2(pA.x + pB.x, pA.y + pB.y);
      const float2 O = make_float2(pA.x - pB.x, pA.y - pB.y);
      const float2 Ow = cmulp(O, wtab_g[k]);
      Yw[wid][pr][k] = make_float2(E.x - Ow.y, E.y + Ow.x);   // Z = E + i*Ow
    }
    WSYNC();   // Z visible to my wave's 1b

    // ---- stage 1b: in-place DFT-8 over the stride-45 set + exact W360 twiddle, per pair.
    if (lane < 45) {
      const int K2 = lane;
#pragma unroll 1
      for (int pp = 0; pp < 2; ++pp) {
        float2 zin[8];
#pragma unroll
        for (int q1 = 0; q1 < 8; ++q1) zin[q1] = Yw[wid][pp][45 * q1 + K2];
        float2 X[8];
        dft8_pos(zin, X);
        int m = 0;                               // m = 2*K2*n1 <= 616: no mod needed
#pragma unroll
        for (int n1 = 0; n1 < 8; ++n1) {
          Yw[wid][pp][n1 * 45 + K2] = cmulp(X[n1], wtab_g[m]);   // exact W360^{K2*n1}
          m += 2 * K2;
        }
      }
    }
    WSYNC();   // my wave's Yw writes visible to my wave's stage-2 reads

    // ---- stage 2: DFT-45 per n1-row (9x5 CT): 72 (row,col) tasks over 64 lanes, 2 fenced passes.
    {
      auto s2_task = [&](int t, int pp) {
        const int n1 = t / 9;
        const int c  = t - 9 * n1;
        const float2* Yrow = &Yw[wid][pp][n1 * 45];
        float yr[5], yi[5];
#pragma unroll
        for (int d = 0; d < 5; ++d) { yr[d] = 0.f; yi[d] = 0.f; }
#pragma unroll 1
        for (int bq = 0; bq < 5; ++bq) {
          float ur = 0.f, ui = 0.f;
#pragma unroll
          for (int a = 0; a < 9; ++a) {
            const float2 zv = Yrow[5 * a + bq];   // scalar LDS loads: no z[9] register array
            const float2 tv = t9[9 * a + c];
            ur += zv.x * tv.x - zv.y * tv.y;
            ui += zv.x * tv.y + zv.y * tv.x;
          }
          const float2 tw = t45[9 * bq + c];
          const float vr = ur * tw.x - ui * tw.y;
          const float vi = ur * tw.y + ui * tw.x;
#pragma unroll
          for (int d = 0; d < 5; ++d) {
            const int m = (bq * d) % 5;           // compile-time
            yr[d] += vr * W5X[m] - vi * W5Y[m];
            yi[d] += vr * W5Y[m] + vi * W5X[m];
          }
        }
        float2* cc2 = (float2*)(&ccw[wid][pp][0]);
#pragma unroll
        for (int d = 0; d < 5; ++d)
          cc2[n1 + 8 * (c + 9 * d)] = make_float2(yr[d], yi[d]);   // cc[2n], cc[2n+1]
      };
#pragma unroll 1
      for (int pp = 0; pp < 2; ++pp) {
        s2_task(lane, pp);                       // pass 0: tasks 0..63
        __builtin_amdgcn_sched_barrier(0);       // fence: do NOT interleave pass chains (R11 lesson)
        if (lane < 8) s2_task(64 + lane, pp);    // pass 1: tasks 64..71
        __builtin_amdgcn_sched_barrier(0);
      }
    }
    WSYNC();   // ccw writes visible to my wave's scans

    // ---- merged peak scans, half-wave per row (lanes 0-31: pair A, 32-63: pair B).
    {
      const int half = lane >> 5, sl = lane & 31;
      const int c2h = c2A + half;
      const float* cr = ccw[wid][half];
      float bvF = 0.f; int btF = 1;
      float bvM = 0.f; int uM  = 719;      // -> t' = 1 on all-zero
      for (int i = sl; i < 719; i += 32) {
        const int u = i + 1;               // 1..719
        const float v  = fabsf(cr[u]);
        const float lf = fabsf(cr[u - 1]);
        const float rt = fabsf(cr[(u == 719) ? 0 : (u + 1)]);
        if (v >= lf && v >= rt) {
          if (u <= 718 && (v > bvF || (v == bvF && u < btF))) { bvF = v; btF = u; }
          if (u >= 2   && (v > bvM || (v == bvM && u > uM)))  { bvM = v; uM  = u; }
        }
      }
      for (int off = 16; off; off >>= 1) {
        const float ovF = __shfl_down(bvF, off, 32); const int otF = __shfl_down(btF, off, 32);
        if (ovF > bvF || (ovF == bvF && otF < btF)) { bvF = ovF; btF = otF; }
        const float ovM = __shfl_down(bvM, off, 32); const int ouM = __shfl_down(uM, off, 32);
        if (ovM > bvM || (ovM == bvM && ouM > uM)) { bvM = ovM; uM = ouM; }
      }
      if (sl == 0 && c2h >= c1) {
        const float rF = (bvF > 0.f) ? cr[btF] * SCALE : 0.f;
        const size_t o = ((size_t)(b * C_ + c1)) * C_ + c2h;
        r_arr[o] = rF; t_arr[o] = btF;
        if (c2h > c1) {
          const float rM = (bvM > 0.f) ? cr[uM] * SCALE : 0.f;
          const size_t o2 = ((size_t)(b * C_ + c2h)) * C_ + c1;
          r_arr[o2] = rM; t_arr[o2] = 720 - uM;
        }
      }
    }
    WSYNC();   // scans' ccw reads done before next it overwrites
  }
}

// ---------------------------------------------------------------- K34: leaders/softmax/filt + spectral mix + output (fused; filt/leads stay in LDS)
__global__ __launch_bounds__(256) void k34_fused(const float* __restrict__ x,
                                                 const float* __restrict__ temperature,
                                                 const float* __restrict__ cls_w,
                                                 const float* __restrict__ basic_state,
                                                 const float* __restrict__ state_bias,
                                                 const float* __restrict__ mhw,
                                                 const float* __restrict__ mhb,
                                                 const float* __restrict__ r_arr,
                                                 const int* __restrict__ t_arr,
                                                 const float* __restrict__ seq,
                                                 const float* __restrict__ mu_g,
                                                 const float* __restrict__ std_g,
                                                 const float* __restrict__ mwr,
                                                 const float* __restrict__ mwi,
                                                 const float* __restrict__ mbr,
                                                 const float* __restrict__ mbi,
                                                 float* __restrict__ out) {
  const int bc = blockIdx.x;
  const int b = bc >> 7, c = bc & 127;
  const int tid = threadIdx.x;
  __shared__ float caL[C_], rL[C_];
  __shared__ int tL[C_];
  __shared__ float xrowL[L_];
  __shared__ float cfL[K_], srL[K_], pL[S_], qL[S_ * K_], praw[S_];
  __shared__ int leadL[K_], ltL[K_];
  __shared__ float cosT[96], sinT[96];
  __shared__ float ssL[K_][H_], ynL[H_], flL[OUT_];
  __shared__ float sfr[K_][F2_], sfi[K_][F2_], yfr[F2_], yfi[F2_];
  __shared__ float catr[3 * F2_], cati[3 * F2_], ofr[F2_], ofi[F2_];

  // ---- gather inputs (k3 part + k4 tables)
  const float* xb = x + (size_t)b * L_ * C_ + c;
  for (int l = tid; l < L_; l += 256) xrowL[l] = xb[(size_t)l * C_];
  if (tid < C_) {
    const float r = r_arr[(size_t)bc * C_ + tid];
    rL[tid] = r; caL[tid] = fabsf(r);
    tL[tid] = t_arr[(size_t)bc * C_ + tid];
  }
  if (tid >= 128 && tid < 224) {
    const int h = tid - 128;
    const float ang = (float)h * (float)(6.283185307179586 / 96.0);
    cosT[h] = cosf(ang); sinT[h] = sinf(ang);
    ynL[h] = seq[(size_t)bc * SEQLEN + L_ + h];
  }
  __syncthreads();

  // ---- top-k leaders + corr softmax (serial, tiny)
  if (tid == 0) {
    const float T = temperature[0];
    float lg[K_ + 1];
    lg[0] = 1.0f / T;
    for (int k = 0; k < K_; ++k) {       // stable top-k: strict > keeps smallest index on ties
      float bvv = -1.f; int bi = 0;
      for (int jj = 0; jj < C_; ++jj) { const float v = caL[jj]; if (v > bvv) { bvv = v; bi = jj; } }
      leadL[k] = bi; ltL[k] = tL[bi];
      const float rv = rL[bi];
      srL[k] = (rv > 0.f) ? 1.f : ((rv < 0.f) ? -1.f : 0.f);
      lg[k + 1] = bvv / T;
      caL[bi] = -2.f;
    }
    float m = lg[0];
    for (int k = 1; k <= K_; ++k) m = fmaxf(m, lg[k]);
    float sum = 0.f, e[K_ + 1];
    for (int k = 0; k <= K_; ++k) { e[k] = expf(lg[k] - m); sum += e[k]; }
    const float invs = 1.0f / sum;
    for (int k = 0; k < K_; ++k) cfL[k] = e[k + 1] * invs;
  }

  // ---- p logits: 8 groups of 32 lanes
  {
    const int gg = tid >> 5, lane = tid & 31;
    float acc = 0.f;
    const float* w = cls_w + (size_t)gg * L_;
    for (int l = lane; l < L_; l += 32) acc += xrowL[l] * w[l];
    for (int off = 16; off; off >>= 1) acc += __shfl_down(acc, off, 32);
    if (lane == 0) praw[gg] = acc + state_bias[gg] + basic_state[c * S_ + gg];
  }
  __syncthreads();
  if (tid == 0) {
    float m = praw[0];
    for (int s2 = 1; s2 < S_; ++s2) m = fmaxf(m, praw[s2]);
    float sum = 0.f;
    for (int s2 = 0; s2 < S_; ++s2) { const float e = expf(praw[s2] - m); pL[s2] = e; sum += e; }
    const float invs = 1.0f / sum;
    for (int s2 = 0; s2 < S_; ++s2) pL[s2] *= invs;
    for (int s2 = 0; s2 < S_; ++s2)
      for (int k = 0; k < K_; ++k) qL[s2 * K_ + k] = pL[s2] * cfL[k];
  }
  __syncthreads();

  // ---- filt -> LDS; leader window gather (both depend on step above)
  for (int o = tid; o < OUT_; o += 256) {
    float acc = 0.f;
#pragma unroll
    for (int s2 = 0; s2 < S_; ++s2) {
      acc += pL[s2] * mhb[s2 * OUT_ + o];
#pragma unroll
      for (int k = 0; k < K_; ++k)
        acc += qL[s2 * K_ + k] * mhw[(size_t)s2 * (K_ * OUT_) + k * OUT_ + o];
    }
    flL[o] = acc;
  }
  for (int i = tid; i < K_ * H_; i += 256) {
    const int k = i / H_, h = i - k * H_;
    ssL[k][h] = seq[((size_t)(b * C_ + leadL[k])) * SEQLEN + (L_ + h - ltL[k])] * srL[k];
  }
  __syncthreads();

  // ---- 96-pt rfft (DFT) of ss rows and yn
  for (int u = tid; u < K_ * F2_ + F2_; u += 256) {
    if (u < K_ * F2_) {
      const int k = u / F2_, f = u - k * F2_;
      float re = 0.f, im = 0.f; int m = 0;
      for (int h = 0; h < H_; ++h) {
        const float v = ssL[k][h];
        re = fmaf(v, cosT[m], re); im = fmaf(-v, sinT[m], im);
        m += f; if (m >= 96) m -= 96;
      }
      sfr[k][f] = re; sfi[k][f] = im;
    } else {
      const int f = u - K_ * F2_;
      float re = 0.f, im = 0.f; int m = 0;
      for (int h = 0; h < H_; ++h) {
        const float v = ynL[h];
        re = fmaf(v, cosT[m], re); im = fmaf(-v, sinT[m], im);
        m += f; if (m >= 96) m -= 96;
      }
      yfr[f] = re; yfi[f] = im;
    }
  }
  __syncthreads();

  if (tid < F2_) {
    const int f = tid;
    float s1r = 0.f, s1i = 0.f, s2r = 0.f, s2i = 0.f;
    const float yr = yfr[f], yi = yfi[f];
#pragma unroll
    for (int k = 0; k < K_; ++k) {
      const float fa = flL[k * F2_ + f], fb = flL[(K_ + k) * F2_ + f];
      const float ar = sfr[k][f] * fa, ai = sfi[k][f] * fa;
      s1r += ar; s1i += ai;
      s2r += (ar - yr) * fb; s2i += (ai - yi) * fb;
    }
    const float fc = flL[2 * K_ * F2_ + f];
    catr[f] = s1r;            cati[f] = s1i;
    catr[F2_ + f] = s2r;      cati[F2_ + f] = s2i;
    catr[2 * F2_ + f] = yr * fc; cati[2 * F2_ + f] = yi * fc;
  }
  __syncthreads();

  if (tid < F2_) {
    const int o = tid;
    float ar = mbr[o], ai = mbi[o];
    const float* wr = mwr + (size_t)o * (3 * F2_);
    const float* wi = mwi + (size_t)o * (3 * F2_);
    for (int f = 0; f < 3 * F2_; ++f) {
      const float cr = catr[f], ci = cati[f];
      const float wrr = wr[f], wii = wi[f];
      ar += cr * wrr - ci * wii;
      ai += cr * wii + ci * wrr;
    }
    ofr[o] = ar; ofi[o] = ai;
  }
  __syncthreads();

  if (tid < H_) {
    const int h = tid;
    float val = ofr[0] + ofr[48] * ((h & 1) ? -1.f : 1.f);
    int m = h;                                  // (f*h)%96 for f=1
    for (int f = 1; f < 48; ++f) {
      val += 2.f * (ofr[f] * cosT[m] - ofi[f] * sinT[m]);
      m += h; if (m >= 96) m -= 96;
    }
    val *= (1.0f / 96.0f);
    const float mu = mu_g[bc], stdv = std_g[bc];
    out[((size_t)b * H_ + h) * C_ + c] = (ynL[h] + val) * stdv + mu;
  }
}

// ---------------------------------------------------------------- launch
extern "C" void kernel_launch(void* const* d_in, const int* in_sizes, int n_in,
                              void* d_out, int out_size, void* d_ws, size_t ws_size,
                              hipStream_t stream) {
  const float* x    = (const float*)d_in[0];
  const float* yh   = (const float*)d_in[1];
  const float* temp = (const float*)d_in[2];
  const float* clsw = (const float*)d_in[3];
  const float* bst  = (const float*)d_in[4];
  const float* sbias= (const float*)d_in[5];
  const float* mhw  = (const float*)d_in[6];
  const float* mhb  = (const float*)d_in[7];
  const float* mwr  = (const float*)d_in[8];
  const float* mwi  = (const float*)d_in[9];
  const float* mbr  = (const float*)d_in[10];
  const float* mbi  = (const float*)d_in[11];
  float* out = (float*)d_out;

  float* ws = (float*)d_ws;
  float* seq    = ws;                                   // 2048*816
  float* mu_g   = seq + (size_t)2048 * SEQLEN;          // 2048
  float* std_g  = mu_g + 2048;                          // 2048
  float* r_arr  = std_g + 2048;                         // 262144
  int*   t_arr  = (int*)(r_arr + (size_t)2048 * C_);    // 262144
  float2* Rc    = (float2*)(t_arr + (size_t)2048 * C_); // 2048*361 float2
  float2* wtab  = Rc + (size_t)2048 * NF;               // 720 float2

  hipLaunchKernelGGL(k0_tab, dim3(1), dim3(256), 0, stream, wtab);
  hipLaunchKernelGGL(k1_fused, dim3(B_ * C_ / 2), dim3(256), 0, stream, x, yh, wtab, seq, mu_g, std_g, Rc);
  hipLaunchKernelGGL(k2_fft, dim3(B_ * 576), dim3(256), 0, stream, Rc, wtab, r_arr, t_arr);
  hipLaunchKernelGGL(k34_fused, dim3(B_ * C_), dim3(256), 0, stream,
                     x, temp, clsw, bst, sbias, mhw, mhb, r_arr, t_arr,
                     seq, mu_g, std_g, mwr, mwi, mbr, mbi, out);
}

// Round 17
// 855.756 us; speedup vs baseline: 1.1042x; 1.1042x over previous
//
#include <hip/hip_runtime.h>
#include <math.h>

#define B_ 16
#define L_ 720
#define C_ 128
#define H_ 96
#define F2_ 49
#define K_ 8
#define S_ 8
#define OUT_ 833          // F2*(2K+1)
#define SEQLEN 816        // L + H
#define NF 361            // rfft bins for L=720

__device__ __forceinline__ float2 cmulp(float2 a, float2 w) {   // a * w (complex)
  return make_float2(a.x*w.x - a.y*w.y, a.x*w.y + a.y*w.x);
}

// Per-wave LDS fence: all my LDS ops done, and no compiler reordering across it (rule #18).
#define WSYNC() do { asm volatile("s_waitcnt lgkmcnt(0)" ::: "memory"); __builtin_amdgcn_sched_barrier(0); } while (0)

// W5^m = e^{+2*pi*i*m/5}
__device__ __constant__ float W5X[5] = {1.f, 0.30901699437494742f, -0.80901699437494745f, -0.80901699437494745f, 0.30901699437494742f};
__device__ __constant__ float W5Y[5] = {0.f, 0.95105651629515357f, 0.58778525229247312f, -0.58778525229247312f, -0.95105651629515357f};

// DFT-8, positive exponent (omega = e^{+i*pi/4}) — verified in R9.
__device__ __forceinline__ void dft8_pos(const float2 zin[8], float2 X[8]) {
  const float RH = 0.70710678118654752440f;
  const float2 A0 = make_float2(zin[0].x+zin[4].x, zin[0].y+zin[4].y);
  const float2 A1 = make_float2(zin[0].x-zin[4].x, zin[0].y-zin[4].y);
  const float2 A2 = make_float2(zin[2].x+zin[6].x, zin[2].y+zin[6].y);
  const float2 A3 = make_float2(zin[2].x-zin[6].x, zin[2].y-zin[6].y);
  const float2 A4 = make_float2(zin[1].x+zin[5].x, zin[1].y+zin[5].y);
  const float2 A5 = make_float2(zin[1].x-zin[5].x, zin[1].y-zin[5].y);
  const float2 A6 = make_float2(zin[3].x+zin[7].x, zin[3].y+zin[7].y);
  const float2 A7 = make_float2(zin[3].x-zin[7].x, zin[3].y-zin[7].y);
  const float2 B0 = make_float2(A0.x+A2.x, A0.y+A2.y);
  const float2 B1 = make_float2(A0.x-A2.x, A0.y-A2.y);
  const float2 B2 = make_float2(A4.x+A6.x, A4.y+A6.y);
  const float2 B3 = make_float2(A4.x-A6.x, A4.y-A6.y);
  X[0] = make_float2(B0.x+B2.x, B0.y+B2.y);
  X[4] = make_float2(B0.x-B2.x, B0.y-B2.y);
  X[2] = make_float2(B1.x - B3.y, B1.y + B3.x);   // B1 + i*B3
  X[6] = make_float2(B1.x + B3.y, B1.y - B3.x);   // B1 - i*B3
  const float2 CI   = make_float2(-A3.y, A3.x);   // i*A3
  const float2 W1s1 = make_float2((A5.x - A5.y)*RH, (A5.x + A5.y)*RH);   // w^1*A5
  const float2 W3s1 = make_float2((-A5.x - A5.y)*RH, (A5.x - A5.y)*RH);  // w^3*A5
  const float2 W1s3 = make_float2((A7.x - A7.y)*RH, (A7.x + A7.y)*RH);   // w^1*A7
  const float2 W3s3 = make_float2((-A7.x - A7.y)*RH, (A7.x - A7.y)*RH);  // w^3*A7
  X[1] = make_float2(A1.x + CI.x + W1s1.x + W3s3.x, A1.y + CI.y + W1s1.y + W3s3.y);
  X[5] = make_float2(A1.x + CI.x - W1s1.x - W3s3.x, A1.y + CI.y - W1s1.y - W3s3.y);
  X[3] = make_float2(A1.x - CI.x + W3s1.x + W1s3.x, A1.y - CI.y + W3s1.y + W1s3.y);
  X[7] = make_float2(A1.x - CI.x - W3s1.x - W1s3.x, A1.y - CI.y - W3s1.y - W1s3.y);
}

// ---------------------------------------------------------------- K0: twiddle table (once per launch)
__global__ __launch_bounds__(256) void k0_tab(float2* __restrict__ wtab_g) {
  for (int k = threadIdx.x; k < L_; k += 256) {
    double ang = (double)k * 0.008726646259971647884;   // 2*pi/720
    wtab_g[k] = make_float2((float)cos(ang), (float)sin(ang));
  }
}

// ---------------------------------------------------------------- K1: normalize + forward rfft, 2 adjacent channels per block
__global__ __launch_bounds__(256) void k1_fused(const float* __restrict__ x,
                                                const float* __restrict__ yh,
                                                const float2* __restrict__ wtab_g,
                                                float* __restrict__ seq,
                                                float* __restrict__ mu_g,
                                                float* __restrict__ std_g,
                                                float2* __restrict__ Rc) {
  const int bc0 = blockIdx.x * 2;       // channels bc0, bc0+1 (adjacent c -> float2 loads)
  const int b = bc0 >> 7, c0 = bc0 & 127;
  const int tid = threadIdx.x;
  __shared__ float xrow[2][L_];
  __shared__ float yrow[2][H_];
  __shared__ float2 wt[L_];
  __shared__ float red[4];

  const float* xb = x + (size_t)b * L_ * C_ + c0;
  for (int l = tid; l < L_; l += 256) {
    const float2 v = *(const float2*)&xb[(size_t)l * C_];
    xrow[0][l] = v.x; xrow[1][l] = v.y;
  }
  const float* yb = yh + (size_t)b * H_ * C_ + c0;
  if (tid < H_) {
    const float2 v = *(const float2*)&yb[(size_t)tid * C_];
    yrow[0][tid] = v.x; yrow[1][tid] = v.y;
  }
  for (int k = tid; k < L_; k += 256) wt[k] = wtab_g[k];
  __syncthreads();

  for (int ch = 0; ch < 2; ++ch) {
    float s = 0.f;
    for (int l = tid; l < L_; l += 256) s += xrow[ch][l];
    for (int off = 32; off; off >>= 1) s += __shfl_down(s, off, 64);
    if ((tid & 63) == 0) red[tid >> 6] = s;
    __syncthreads();
    const float mu = (red[0] + red[1] + red[2] + red[3]) * (1.0f / L_);
    __syncthreads();
    float vs = 0.f;
    for (int l = tid; l < L_; l += 256) { float d = xrow[ch][l] - mu; vs += d * d; }
    for (int off = 32; off; off >>= 1) vs += __shfl_down(vs, off, 64);
    if ((tid & 63) == 0) red[tid >> 6] = vs;
    __syncthreads();
    const float stdv = sqrtf((red[0] + red[1] + red[2] + red[3]) * (1.0f / L_) + 1e-8f);
    const float inv = 1.0f / stdv;
    if (tid == 0) { mu_g[bc0 + ch] = mu; std_g[bc0 + ch] = stdv; }
    __syncthreads();                     // red reused next ch; also xrow rewrite guard
    float* sq = seq + (size_t)(bc0 + ch) * SEQLEN;
    for (int l = tid; l < L_; l += 256) { const float v = (xrow[ch][l] - mu) * inv; xrow[ch][l] = v; sq[l] = v; }
    if (tid < H_) sq[L_ + tid] = (yrow[ch][tid] - mu) * inv;
    __syncthreads();
  }

  for (int u = tid; u < 2 * NF; u += 256) {   // rfft (negative exponent), from normalized LDS rows
    const int row = u / NF, f = u - row * NF;
    float re = 0.f, im = 0.f;
    int m = 0;
    const float* xr = xrow[row];
    for (int l = 0; l < L_; ++l) {
      const float v = xr[l];
      const float2 w = wt[m];
      re = fmaf(v, w.x, re);
      im = fmaf(-v, w.y, im);
      m += f; if (m >= L_) m -= L_;
    }
    Rc[(size_t)(bc0 + row) * NF + f] = make_float2(re, im);
  }
}

// ---------------------------------------------------------------- K2: per-wave spectral product + real-packed 360-pt IFFT, 1 pair/wave/iter
// cc (real, len 720) via z[n] = cc[2n] + i*cc[2n+1] = IDFT360(Z); Z from Hermitian P (see R9).
// R17: 1 pair per wave-iteration halves Yw/ccw -> LDS ~27 KB -> 5 blocks/CU by LDS; VGPR ~68
// allows 4 waves/SIMD -> ~50% occupancy (R16 was LDS-capped at 30%). Latency hiding now comes
// from cross-wave TLP (waves are barrier-free after init) instead of in-wave ILP.
// Stage-1 split through LDS (1a Z-build, 1b in-place DFT-8); stage-2 = 72 fenced single-column
// tasks (R16's spill-free form). Spill detector: WRITE_SIZE must stay ~2 MB.
__global__ __launch_bounds__(256, 3) void k2_fft(const float2* __restrict__ Rc,
                                                 const float2* __restrict__ wtab_g,
                                                 float* __restrict__ r_arr,
                                                 int* __restrict__ t_arr) {
  // XCD-aware bijective swizzle (T1): grid = 9216 = 8 * 1152 -> each XCD gets 2 contiguous batches.
  const int phys = blockIdx.x;
  int idx = (phys & 7) * 1152 + (phys >> 3);
  const int b = idx / 576;
  idx -= b * 576;
  int g = 0;
  while (true) { const int cnt = (8 - g) << 4; if (idx < cnt) break; idx -= cnt; ++g; }
  const int rows = 8 - g;
  const int c1 = (g << 4) + idx / rows;
  const int c2t = g + idx % rows;
  const int c2base = c2t << 4;
  const int tid = threadIdx.x;
  const int wid = tid >> 6, lane = tid & 63;

  __shared__ float2 r1c[NF];
  __shared__ float2 t9[81];                   // W9^{a*c} at [9a+c]
  __shared__ float2 t45[45];                  // W45^{b*c} at [9b+c]
  __shared__ float2 Yw[4][360];               // per-wave: Z then stage-1 out (in place)
  __shared__ __align__(16) float ccw[4][728]; // per-wave cc row

  for (int f = tid; f < NF; f += 256) r1c[f] = Rc[((size_t)(b * C_ + c1)) * NF + f];
  for (int i = tid; i < 81; i += 256) { int a = i / 9, c = i % 9; t9[i] = wtab_g[80 * ((a * c) % 9)]; }
  for (int i = tid; i < 45; i += 256) { int bb = i / 9, c = i % 9; t45[i] = wtab_g[16 * bb * c]; }
  __syncthreads();                   // the only block-wide barrier

  const float SCALE = 1.0f / 518400.0f;   // 1/720^2

  for (int j = 0; j < 4; ++j) {
    const int c2 = c2base + (wid << 2) + j;
    if (c2 < c1) continue;           // diagonal-tile waste: nothing would be emitted
    const float2* R2 = Rc + ((size_t)(b * C_ + c2)) * NF;   // L2-hot after swizzle

    // ---- stage 1a: Z build -> Yw. Tiny per-task register footprint, coalesced loads.
    for (int k = lane; k < 360; k += 64) {
      const int fB = 360 - k;                  // in [1, 360]
      const float2 a1 = r1c[k];
      const float2 a2 = r1c[fB];
      const float2 b1 = R2[k];
      const float2 b2 = R2[fB];
      const float2 pA = make_float2(a1.x*b1.x + a1.y*b1.y, a1.y*b1.x - a1.x*b1.y);
      float2 pB = make_float2(a2.x*b2.x + a2.y*b2.y, a2.y*b2.x - a2.x*b2.y);
      pB.y = (k == 0) ? pB.y : -pB.y;          // conj for k>=1
      const float2 E = make_float2(pA.x + pB.x, pA.y + pB.y);
      const float2 O = make_float2(pA.x - pB.x, pA.y - pB.y);
      const float2 Ow = cmulp(O, wtab_g[k]);
      Yw[wid][k] = make_float2(E.x - Ow.y, E.y + Ow.x);   // Z = E + i*Ow
    }
    WSYNC();   // Z visible to my wave's 1b

    // ---- stage 1b: in-place DFT-8 over the stride-45 set + exact W360 twiddle.
    if (lane < 45) {
      const int K2 = lane;
      float2 zin[8];
#pragma unroll
      for (int q1 = 0; q1 < 8; ++q1) zin[q1] = Yw[wid][45 * q1 + K2];
      float2 X[8];
      dft8_pos(zin, X);
      int m = 0;                               // m = 2*K2*n1 <= 616: no mod needed
#pragma unroll
      for (int n1 = 0; n1 < 8; ++n1) {
        Yw[wid][n1 * 45 + K2] = cmulp(X[n1], wtab_g[m]);   // exact W360^{K2*n1}
        m += 2 * K2;
      }
    }
    WSYNC();   // my wave's Yw writes visible to my wave's stage-2 reads

    // ---- stage 2: DFT-45 per n1-row (9x5 CT): 72 (row,col) tasks over 64 lanes, 2 fenced passes.
    {
      auto s2_task = [&](int t) {
        const int n1 = t / 9;
        const int c  = t - 9 * n1;
        const float2* Yrow = &Yw[wid][n1 * 45];
        float yr[5], yi[5];
#pragma unroll
        for (int d = 0; d < 5; ++d) { yr[d] = 0.f; yi[d] = 0.f; }
#pragma unroll 1
        for (int bq = 0; bq < 5; ++bq) {
          float ur = 0.f, ui = 0.f;
#pragma unroll
          for (int a = 0; a < 9; ++a) {
            const float2 zv = Yrow[5 * a + bq];   // scalar LDS loads: no z[9] register array
            const float2 tv = t9[9 * a + c];
            ur += zv.x * tv.x - zv.y * tv.y;
            ui += zv.x * tv.y + zv.y * tv.x;
          }
          const float2 tw = t45[9 * bq + c];
          const float vr = ur * tw.x - ui * tw.y;
          const float vi = ur * tw.y + ui * tw.x;
#pragma unroll
          for (int d = 0; d < 5; ++d) {
            const int m = (bq * d) % 5;           // compile-time
            yr[d] += vr * W5X[m] - vi * W5Y[m];
            yi[d] += vr * W5Y[m] + vi * W5X[m];
          }
        }
        float2* cc2 = (float2*)(&ccw[wid][0]);
#pragma unroll
        for (int d = 0; d < 5; ++d)
          cc2[n1 + 8 * (c + 9 * d)] = make_float2(yr[d], yi[d]);   // cc[2n], cc[2n+1]
      };
      s2_task(lane);                           // pass 0: tasks 0..63
      __builtin_amdgcn_sched_barrier(0);       // fence: do NOT interleave pass chains (R11 lesson)
      if (lane < 8) s2_task(64 + lane);        // pass 1: tasks 64..71
      __builtin_amdgcn_sched_barrier(0);
    }
    WSYNC();   // ccw writes visible to my wave's scan

    // ---- merged peak scan (fwd + mirror), full wave, width-64 reduce (R9-verified semantics).
    {
      const float* cr = ccw[wid];
      float bvF = 0.f; int btF = 1;
      float bvM = 0.f; int uM  = 719;      // -> t' = 1 on all-zero
      for (int i = lane; i < 719; i += 64) {
        const int u = i + 1;               // 1..719
        const float v  = fabsf(cr[u]);
        const float lf = fabsf(cr[u - 1]);
        const float rt = fabsf(cr[(u == 719) ? 0 : (u + 1)]);
        if (v >= lf && v >= rt) {
          if (u <= 718 && (v > bvF || (v == bvF && u < btF))) { bvF = v; btF = u; }
          if (u >= 2   && (v > bvM || (v == bvM && u > uM)))  { bvM = v; uM  = u; }
        }
      }
      for (int off = 32; off; off >>= 1) {
        const float ovF = __shfl_down(bvF, off, 64); const int otF = __shfl_down(btF, off, 64);
        if (ovF > bvF || (ovF == bvF && otF < btF)) { bvF = ovF; btF = otF; }
        const float ovM = __shfl_down(bvM, off, 64); const int ouM = __shfl_down(uM, off, 64);
        if (ovM > bvM || (ovM == bvM && ouM > uM)) { bvM = ovM; uM = ouM; }
      }
      if (lane == 0) {
        const float rF = (bvF > 0.f) ? cr[btF] * SCALE : 0.f;
        const size_t o = ((size_t)(b * C_ + c1)) * C_ + c2;
        r_arr[o] = rF; t_arr[o] = btF;
        if (c2 > c1) {
          const float rM = (bvM > 0.f) ? cr[uM] * SCALE : 0.f;
          const size_t o2 = ((size_t)(b * C_ + c2)) * C_ + c1;
          r_arr[o2] = rM; t_arr[o2] = 720 - uM;
        }
      }
    }
    WSYNC();   // scan's ccw reads done before next j overwrites
  }
}

// ---------------------------------------------------------------- K34: leaders/softmax/filt + spectral mix + output (fused; filt/leads stay in LDS)
__global__ __launch_bounds__(256) void k34_fused(const float* __restrict__ x,
                                                 const float* __restrict__ temperature,
                                                 const float* __restrict__ cls_w,
                                                 const float* __restrict__ basic_state,
                                                 const float* __restrict__ state_bias,
                                                 const float* __restrict__ mhw,
                                                 const float* __restrict__ mhb,
                                                 const float* __restrict__ r_arr,
                                                 const int* __restrict__ t_arr,
                                                 const float* __restrict__ seq,
                                                 const float* __restrict__ mu_g,
                                                 const float* __restrict__ std_g,
                                                 const float* __restrict__ mwr,
                                                 const float* __restrict__ mwi,
                                                 const float* __restrict__ mbr,
                                                 const float* __restrict__ mbi,
                                                 float* __restrict__ out) {
  const int bc = blockIdx.x;
  const int b = bc >> 7, c = bc & 127;
  const int tid = threadIdx.x;
  __shared__ float caL[C_], rL[C_];
  __shared__ int tL[C_];
  __shared__ float xrowL[L_];
  __shared__ float cfL[K_], srL[K_], pL[S_], qL[S_ * K_], praw[S_];
  __shared__ int leadL[K_], ltL[K_];
  __shared__ float cosT[96], sinT[96];
  __shared__ float ssL[K_][H_], ynL[H_], flL[OUT_];
  __shared__ float sfr[K_][F2_], sfi[K_][F2_], yfr[F2_], yfi[F2_];
  __shared__ float catr[3 * F2_], cati[3 * F2_], ofr[F2_], ofi[F2_];

  // ---- gather inputs (k3 part + k4 tables)
  const float* xb = x + (size_t)b * L_ * C_ + c;
  for (int l = tid; l < L_; l += 256) xrowL[l] = xb[(size_t)l * C_];
  if (tid < C_) {
    const float r = r_arr[(size_t)bc * C_ + tid];
    rL[tid] = r; caL[tid] = fabsf(r);
    tL[tid] = t_arr[(size_t)bc * C_ + tid];
  }
  if (tid >= 128 && tid < 224) {
    const int h = tid - 128;
    const float ang = (float)h * (float)(6.283185307179586 / 96.0);
    cosT[h] = cosf(ang); sinT[h] = sinf(ang);
    ynL[h] = seq[(size_t)bc * SEQLEN + L_ + h];
  }
  __syncthreads();

  // ---- top-k leaders + corr softmax (serial, tiny)
  if (tid == 0) {
    const float T = temperature[0];
    float lg[K_ + 1];
    lg[0] = 1.0f / T;
    for (int k = 0; k < K_; ++k) {       // stable top-k: strict > keeps smallest index on ties
      float bvv = -1.f; int bi = 0;
      for (int jj = 0; jj < C_; ++jj) { const float v = caL[jj]; if (v > bvv) { bvv = v; bi = jj; } }
      leadL[k] = bi; ltL[k] = tL[bi];
      const float rv = rL[bi];
      srL[k] = (rv > 0.f) ? 1.f : ((rv < 0.f) ? -1.f : 0.f);
      lg[k + 1] = bvv / T;
      caL[bi] = -2.f;
    }
    float m = lg[0];
    for (int k = 1; k <= K_; ++k) m = fmaxf(m, lg[k]);
    float sum = 0.f, e[K_ + 1];
    for (int k = 0; k <= K_; ++k) { e[k] = expf(lg[k] - m); sum += e[k]; }
    const float invs = 1.0f / sum;
    for (int k = 0; k < K_; ++k) cfL[k] = e[k + 1] * invs;
  }

  // ---- p logits: 8 groups of 32 lanes
  {
    const int gg = tid >> 5, lane = tid & 31;
    float acc = 0.f;
    const float* w = cls_w + (size_t)gg * L_;
    for (int l = lane; l < L_; l += 32) acc += xrowL[l] * w[l];
    for (int off = 16; off; off >>= 1) acc += __shfl_down(acc, off, 32);
    if (lane == 0) praw[gg] = acc + state_bias[gg] + basic_state[c * S_ + gg];
  }
  __syncthreads();
  if (tid == 0) {
    float m = praw[0];
    for (int s2 = 1; s2 < S_; ++s2) m = fmaxf(m, praw[s2]);
    float sum = 0.f;
    for (int s2 = 0; s2 < S_; ++s2) { const float e = expf(praw[s2] - m); pL[s2] = e; sum += e; }
    const float invs = 1.0f / sum;
    for (int s2 = 0; s2 < S_; ++s2) pL[s2] *= invs;
    for (int s2 = 0; s2 < S_; ++s2)
      for (int k = 0; k < K_; ++k) qL[s2 * K_ + k] = pL[s2] * cfL[k];
  }
  __syncthreads();

  // ---- filt -> LDS; leader window gather (both depend on step above)
  for (int o = tid; o < OUT_; o += 256) {
    float acc = 0.f;
#pragma unroll
    for (int s2 = 0; s2 < S_; ++s2) {
      acc += pL[s2] * mhb[s2 * OUT_ + o];
#pragma unroll
      for (int k = 0; k < K_; ++k)
        acc += qL[s2 * K_ + k] * mhw[(size_t)s2 * (K_ * OUT_) + k * OUT_ + o];
    }
    flL[o] = acc;
  }
  for (int i = tid; i < K_ * H_; i += 256) {
    const int k = i / H_, h = i - k * H_;
    ssL[k][h] = seq[((size_t)(b * C_ + leadL[k])) * SEQLEN + (L_ + h - ltL[k])] * srL[k];
  }
  __syncthreads();

  // ---- 96-pt rfft (DFT) of ss rows and yn
  for (int u = tid; u < K_ * F2_ + F2_; u += 256) {
    if (u < K_ * F2_) {
      const int k = u / F2_, f = u - k * F2_;
      float re = 0.f, im = 0.f; int m = 0;
      for (int h = 0; h < H_; ++h) {
        const float v = ssL[k][h];
        re = fmaf(v, cosT[m], re); im = fmaf(-v, sinT[m], im);
        m += f; if (m >= 96) m -= 96;
      }
      sfr[k][f] = re; sfi[k][f] = im;
    } else {
      const int f = u - K_ * F2_;
      float re = 0.f, im = 0.f; int m = 0;
      for (int h = 0; h < H_; ++h) {
        const float v = ynL[h];
        re = fmaf(v, cosT[m], re); im = fmaf(-v, sinT[m], im);
        m += f; if (m >= 96) m -= 96;
      }
      yfr[f] = re; yfi[f] = im;
    }
  }
  __syncthreads();

  if (tid < F2_) {
    const int f = tid;
    float s1r = 0.f, s1i = 0.f, s2r = 0.f, s2i = 0.f;
    const float yr = yfr[f], yi = yfi[f];
#pragma unroll
    for (int k = 0; k < K_; ++k) {
      const float fa = flL[k * F2_ + f], fb = flL[(K_ + k) * F2_ + f];
      const float ar = sfr[k][f] * fa, ai = sfi[k][f] * fa;
      s1r += ar; s1i += ai;
      s2r += (ar - yr) * fb; s2i += (ai - yi) * fb;
    }
    const float fc = flL[2 * K_ * F2_ + f];
    catr[f] = s1r;            cati[f] = s1i;
    catr[F2_ + f] = s2r;      cati[F2_ + f] = s2i;
    catr[2 * F2_ + f] = yr * fc; cati[2 * F2_ + f] = yi * fc;
  }
  __syncthreads();

  if (tid < F2_) {
    const int o = tid;
    float ar = mbr[o], ai = mbi[o];
    const float* wr = mwr + (size_t)o * (3 * F2_);
    const float* wi = mwi + (size_t)o * (3 * F2_);
    for (int f = 0; f < 3 * F2_; ++f) {
      const float cr = catr[f], ci = cati[f];
      const float wrr = wr[f], wii = wi[f];
      ar += cr * wrr - ci * wii;
      ai += cr * wii + ci * wrr;
    }
    ofr[o] = ar; ofi[o] = ai;
  }
  __syncthreads();

  if (tid < H_) {
    const int h = tid;
    float val = ofr[0] + ofr[48] * ((h & 1) ? -1.f : 1.f);
    int m = h;                                  // (f*h)%96 for f=1
    for (int f = 1; f < 48; ++f) {
      val += 2.f * (ofr[f] * cosT[m] - ofi[f] * sinT[m]);
      m += h; if (m >= 96) m -= 96;
    }
    val *= (1.0f / 96.0f);
    const float mu = mu_g[bc], stdv = std_g[bc];
    out[((size_t)b * H_ + h) * C_ + c] = (ynL[h] + val) * stdv + mu;
  }
}

// ---------------------------------------------------------------- launch
extern "C" void kernel_launch(void* const* d_in, const int* in_sizes, int n_in,
                              void* d_out, int out_size, void* d_ws, size_t ws_size,
                              hipStream_t stream) {
  const float* x    = (const float*)d_in[0];
  const float* yh   = (const float*)d_in[1];
  const float* temp = (const float*)d_in[2];
  const float* clsw = (const float*)d_in[3];
  const float* bst  = (const float*)d_in[4];
  const float* sbias= (const float*)d_in[5];
  const float* mhw  = (const float*)d_in[6];
  const float* mhb  = (const float*)d_in[7];
  const float* mwr  = (const float*)d_in[8];
  const float* mwi  = (const float*)d_in[9];
  const float* mbr  = (const float*)d_in[10];
  const float* mbi  = (const float*)d_in[11];
  float* out = (float*)d_out;

  float* ws = (float*)d_ws;
  float* seq    = ws;                                   // 2048*816
  float* mu_g   = seq + (size_t)2048 * SEQLEN;          // 2048
  float* std_g  = mu_g + 2048;                          // 2048
  float* r_arr  = std_g + 2048;                         // 262144
  int*   t_arr  = (int*)(r_arr + (size_t)2048 * C_);    // 262144
  float2* Rc    = (float2*)(t_arr + (size_t)2048 * C_); // 2048*361 float2
  float2* wtab  = Rc + (size_t)2048 * NF;               // 720 float2

  hipLaunchKernelGGL(k0_tab, dim3(1), dim3(256), 0, stream, wtab);
  hipLaunchKernelGGL(k1_fused, dim3(B_ * C_ / 2), dim3(256), 0, stream, x, yh, wtab, seq, mu_g, std_g, Rc);
  hipLaunchKernelGGL(k2_fft, dim3(B_ * 576), dim3(256), 0, stream, Rc, wtab, r_arr, t_arr);
  hipLaunchKernelGGL(k34_fused, dim3(B_ * C_), dim3(256), 0, stream,
                     x, temp, clsw, bst, sbias, mhw, mhb, r_arr, t_arr,
                     seq, mu_g, std_g, mwr, mwi, mbr, mbi, out);
}

// Round 18
// 740.338 us; speedup vs baseline: 1.2764x; 1.1559x over previous
//
#include <hip/hip_runtime.h>
#include <math.h>

#define B_ 16
#define L_ 720
#define C_ 128
#define H_ 96
#define F2_ 49
#define K_ 8
#define S_ 8
#define OUT_ 833          // F2*(2K+1)
#define SEQLEN 816        // L + H
#define NF 361            // rfft bins for L=720

__device__ __forceinline__ float2 cmulp(float2 a, float2 w) {   // a * w (complex)
  return make_float2(a.x*w.x - a.y*w.y, a.x*w.y + a.y*w.x);
}

// Per-wave LDS fence: all my LDS ops done, and no compiler reordering across it (rule #18).
#define WSYNC() do { asm volatile("s_waitcnt lgkmcnt(0)" ::: "memory"); __builtin_amdgcn_sched_barrier(0); } while (0)

// W16^{bc} = e^{+2*pi*i*bc/16}, indexed by bc in {1,2,3,4,6,9}  (verified R3-R8)
__device__ __constant__ float W16X[10] = {1.f, 0.9238795325112867f, 0.7071067811865476f, 0.3826834323650898f, 0.f, 0.f, -0.7071067811865476f, 0.f, 0.f, -0.9238795325112867f};
__device__ __constant__ float W16Y[10] = {0.f, 0.3826834323650898f, 0.7071067811865476f, 0.9238795325112867f, 1.f, 0.f, 0.7071067811865476f, 0.f, 0.f, -0.3826834323650898f};
// W5^m = e^{+2*pi*i*m/5}
__device__ __constant__ float W5X[5] = {1.f, 0.30901699437494742f, -0.80901699437494745f, -0.80901699437494745f, 0.30901699437494742f};
__device__ __constant__ float W5Y[5] = {0.f, 0.95105651629515357f, 0.58778525229247312f, -0.58778525229247312f, -0.95105651629515357f};

// DFT-8, positive exponent (omega = e^{+i*pi/4}) — verified in R9.
__device__ __forceinline__ void dft8_pos(const float2 zin[8], float2 X[8]) {
  const float RH = 0.70710678118654752440f;
  const float2 A0 = make_float2(zin[0].x+zin[4].x, zin[0].y+zin[4].y);
  const float2 A1 = make_float2(zin[0].x-zin[4].x, zin[0].y-zin[4].y);
  const float2 A2 = make_float2(zin[2].x+zin[6].x, zin[2].y+zin[6].y);
  const float2 A3 = make_float2(zin[2].x-zin[6].x, zin[2].y-zin[6].y);
  const float2 A4 = make_float2(zin[1].x+zin[5].x, zin[1].y+zin[5].y);
  const float2 A5 = make_float2(zin[1].x-zin[5].x, zin[1].y-zin[5].y);
  const float2 A6 = make_float2(zin[3].x+zin[7].x, zin[3].y+zin[7].y);
  const float2 A7 = make_float2(zin[3].x-zin[7].x, zin[3].y-zin[7].y);
  const float2 B0 = make_float2(A0.x+A2.x, A0.y+A2.y);
  const float2 B1 = make_float2(A0.x-A2.x, A0.y-A2.y);
  const float2 B2 = make_float2(A4.x+A6.x, A4.y+A6.y);
  const float2 B3 = make_float2(A4.x-A6.x, A4.y-A6.y);
  X[0] = make_float2(B0.x+B2.x, B0.y+B2.y);
  X[4] = make_float2(B0.x-B2.x, B0.y-B2.y);
  X[2] = make_float2(B1.x - B3.y, B1.y + B3.x);   // B1 + i*B3
  X[6] = make_float2(B1.x + B3.y, B1.y - B3.x);   // B1 - i*B3
  const float2 CI   = make_float2(-A3.y, A3.x);   // i*A3
  const float2 W1s1 = make_float2((A5.x - A5.y)*RH, (A5.x + A5.y)*RH);   // w^1*A5
  const float2 W3s1 = make_float2((-A5.x - A5.y)*RH, (A5.x - A5.y)*RH);  // w^3*A5
  const float2 W1s3 = make_float2((A7.x - A7.y)*RH, (A7.x + A7.y)*RH);   // w^1*A7
  const float2 W3s3 = make_float2((-A7.x - A7.y)*RH, (A7.x - A7.y)*RH);  // w^3*A7
  X[1] = make_float2(A1.x + CI.x + W1s1.x + W3s3.x, A1.y + CI.y + W1s1.y + W3s3.y);
  X[5] = make_float2(A1.x + CI.x - W1s1.x - W3s3.x, A1.y + CI.y - W1s1.y - W3s3.y);
  X[3] = make_float2(A1.x - CI.x + W3s1.x + W1s3.x, A1.y - CI.y + W3s1.y + W1s3.y);
  X[7] = make_float2(A1.x - CI.x - W3s1.x - W1s3.x, A1.y - CI.y - W3s1.y - W1s3.y);
}

// ---------------------------------------------------------------- K0: twiddle table (once per launch)
__global__ __launch_bounds__(256) void k0_tab(float2* __restrict__ wtab_g) {
  for (int k = threadIdx.x; k < L_; k += 256) {
    double ang = (double)k * 0.008726646259971647884;   // 2*pi/720
    wtab_g[k] = make_float2((float)cos(ang), (float)sin(ang));
  }
}

// ---------------------------------------------------------------- K1: normalize + packed forward rfft (2 channels via one 720-pt FFT)
// v[l] = x0n[l] - i*x1n[l] = conj(x0n + i*x1n); Zp = DFT720_pos(v); Z = conj(Zp) = DFT720_neg(x0n+i*x1n).
// Unpack: zm = Zp[(720-f)%720];  R0[f] = (conj(zf)+zm)/2 ;  R1[f] = -i/2*(conj(zf)-zm).
// 720 = 16x45 CT: stage-1 = 45 DFT-16 (R3-verified u4/g16) + exact W720pos^{n2*k1};
// stage-2 = 16x9 = 144 complex DFT-45 column tasks (k2-verified 9x5 machinery). ~25x fewer FLOPs
// than the naive 361x720 DFT it replaces.
__global__ __launch_bounds__(256) void k1_fused(const float* __restrict__ x,
                                                const float* __restrict__ yh,
                                                const float2* __restrict__ wtab_g,
                                                float* __restrict__ seq,
                                                float* __restrict__ mu_g,
                                                float* __restrict__ std_g,
                                                float2* __restrict__ Rc) {
  const int bc0 = blockIdx.x * 2;       // channels bc0, bc0+1 (adjacent c -> float2 loads)
  const int b = bc0 >> 7, c0 = bc0 & 127;
  const int tid = threadIdx.x;
  __shared__ float xrow[2][L_];
  __shared__ float yrow[2][H_];
  __shared__ float2 wt[L_];
  __shared__ float2 t9s[81];            // W9^{a*c}
  __shared__ float2 t45s[45];           // W45^{bq*c}
  __shared__ float2 Yst[720];           // stage-1 out [k1*45 + n2]
  __shared__ float2 Zp[720];            // stage-2 out (positive-exponent spectrum of v)
  __shared__ float red[4];

  const float* xb = x + (size_t)b * L_ * C_ + c0;
  for (int l = tid; l < L_; l += 256) {
    const float2 v = *(const float2*)&xb[(size_t)l * C_];
    xrow[0][l] = v.x; xrow[1][l] = v.y;
  }
  const float* yb = yh + (size_t)b * H_ * C_ + c0;
  if (tid < H_) {
    const float2 v = *(const float2*)&yb[(size_t)tid * C_];
    yrow[0][tid] = v.x; yrow[1][tid] = v.y;
  }
  for (int k = tid; k < L_; k += 256) wt[k] = wtab_g[k];
  for (int i = tid; i < 81; i += 256) { int a = i / 9, c = i % 9; t9s[i] = wtab_g[80 * ((a * c) % 9)]; }
  for (int i = tid; i < 45; i += 256) { int bb = i / 9, c = i % 9; t45s[i] = wtab_g[16 * bb * c]; }
  __syncthreads();

  for (int ch = 0; ch < 2; ++ch) {
    float s = 0.f;
    for (int l = tid; l < L_; l += 256) s += xrow[ch][l];
    for (int off = 32; off; off >>= 1) s += __shfl_down(s, off, 64);
    if ((tid & 63) == 0) red[tid >> 6] = s;
    __syncthreads();
    const float mu = (red[0] + red[1] + red[2] + red[3]) * (1.0f / L_);
    __syncthreads();
    float vs = 0.f;
    for (int l = tid; l < L_; l += 256) { float d = xrow[ch][l] - mu; vs += d * d; }
    for (int off = 32; off; off >>= 1) vs += __shfl_down(vs, off, 64);
    if ((tid & 63) == 0) red[tid >> 6] = vs;
    __syncthreads();
    const float stdv = sqrtf((red[0] + red[1] + red[2] + red[3]) * (1.0f / L_) + 1e-8f);
    const float inv = 1.0f / stdv;
    if (tid == 0) { mu_g[bc0 + ch] = mu; std_g[bc0 + ch] = stdv; }
    __syncthreads();                     // red reused next ch; also xrow rewrite guard
    float* sq = seq + (size_t)(bc0 + ch) * SEQLEN;
    for (int l = tid; l < L_; l += 256) { const float v = (xrow[ch][l] - mu) * inv; xrow[ch][l] = v; sq[l] = v; }
    if (tid < H_) sq[L_ + tid] = (yrow[ch][tid] - mu) * inv;
    __syncthreads();
  }

  // ---- stage 1: 45 DFT-16 over n1 (n = 45*n1 + n2) + exact twiddle W720pos^{n2*k1}.
  if (tid < 45) {
    const int n2 = tid;
    float2 z[16];
#pragma unroll
    for (int n1 = 0; n1 < 16; ++n1) {
      const int n = 45 * n1 + n2;
      z[n1] = make_float2(xrow[0][n], -xrow[1][n]);   // v = conj(x0n + i*x1n)
    }
    float2 u4[4][4];
#pragma unroll
    for (int bb = 0; bb < 4; ++bb) {
      const float2 p0 = z[bb], p1 = z[4 + bb], p2 = z[8 + bb], p3 = z[12 + bb];
      const float t0r = p0.x + p2.x, t0i = p0.y + p2.y;
      const float t1r = p0.x - p2.x, t1i = p0.y - p2.y;
      const float t2r = p1.x + p3.x, t2i = p1.y + p3.y;
      const float t3r = p1.x - p3.x, t3i = p1.y - p3.y;
      u4[bb][0] = make_float2(t0r + t2r, t0i + t2i);
      u4[bb][2] = make_float2(t0r - t2r, t0i - t2i);
      u4[bb][1] = make_float2(t1r - t3i, t1i + t3r);   // t1 + i*t3
      u4[bb][3] = make_float2(t1r + t3i, t1i - t3r);   // t1 - i*t3
    }
#pragma unroll
    for (int bb = 1; bb < 4; ++bb)
#pragma unroll
      for (int c = 1; c < 4; ++c) {
        const float2 w = make_float2(W16X[bb * c], W16Y[bb * c]);
        u4[bb][c] = cmulp(u4[bb][c], w);
      }
    float2 g16[16];
#pragma unroll
    for (int c = 0; c < 4; ++c) {
      const float2 p0 = u4[0][c], p1 = u4[1][c], p2 = u4[2][c], p3 = u4[3][c];
      const float t0r = p0.x + p2.x, t0i = p0.y + p2.y;
      const float t1r = p0.x - p2.x, t1i = p0.y - p2.y;
      const float t2r = p1.x + p3.x, t2i = p1.y + p3.y;
      const float t3r = p1.x - p3.x, t3i = p1.y - p3.y;
      g16[c + 0]  = make_float2(t0r + t2r, t0i + t2i);
      g16[c + 8]  = make_float2(t0r - t2r, t0i - t2i);
      g16[c + 4]  = make_float2(t1r - t3i, t1i + t3r);
      g16[c + 12] = make_float2(t1r + t3i, t1i - t3r);
    }
    int m = 0;                                   // m = n2*k1 <= 44*15 = 660 < 720: no mod needed
#pragma unroll
    for (int k1 = 0; k1 < 16; ++k1) {
      Yst[k1 * 45 + n2] = cmulp(g16[k1], wt[m]);
      m += n2;
    }
  }
  __syncthreads();

  // ---- stage 2: 16 rows x 9 cols = 144 complex DFT-45 column tasks -> Zp[k1 + 16*(c+9d)].
  if (tid < 144) {
    const int row = tid / 9;
    const int c = tid - 9 * row;
    const float2* Yrow = &Yst[row * 45];
    float yr[5], yi[5];
#pragma unroll
    for (int d = 0; d < 5; ++d) { yr[d] = 0.f; yi[d] = 0.f; }
#pragma unroll 1
    for (int bq = 0; bq < 5; ++bq) {
      float ur = 0.f, ui = 0.f;
#pragma unroll
      for (int a = 0; a < 9; ++a) {
        const float2 zv = Yrow[5 * a + bq];
        const float2 tv = t9s[9 * a + c];
        ur += zv.x * tv.x - zv.y * tv.y;
        ui += zv.x * tv.y + zv.y * tv.x;
      }
      const float2 tw = t45s[9 * bq + c];
      const float vr = ur * tw.x - ui * tw.y;
      const float vi = ur * tw.y + ui * tw.x;
#pragma unroll
      for (int d = 0; d < 5; ++d) {
        const int m = (bq * d) % 5;               // compile-time
        yr[d] += vr * W5X[m] - vi * W5Y[m];
        yi[d] += vr * W5Y[m] + vi * W5X[m];
      }
    }
#pragma unroll
    for (int d = 0; d < 5; ++d)
      Zp[row + 16 * (c + 9 * d)] = make_float2(yr[d], yi[d]);
  }
  __syncthreads();

  // ---- unpack both spectra (f = 0..360) and store.
  for (int f = tid; f < NF; f += 256) {
    const float2 zf = Zp[f];
    const float2 zm = Zp[(720 - f) % 720];
    // R0 = (conj(zf) + zm)/2 ; R1 = -i/2*(conj(zf) - zm)
    Rc[(size_t)bc0 * NF + f]       = make_float2((zf.x + zm.x) * 0.5f, (zm.y - zf.y) * 0.5f);
    Rc[(size_t)(bc0 + 1) * NF + f] = make_float2((-zf.y - zm.y) * 0.5f, (zm.x - zf.x) * 0.5f);
  }
}

// ---------------------------------------------------------------- K2: per-wave spectral product + real-packed 360-pt IFFT, 1 pair/wave/iter
// cc (real, len 720) via z[n] = cc[2n] + i*cc[2n+1] = IDFT360(Z); Z from Hermitian P (see R9).
// R17 structure (best known): 1 pair/wave-iter, LDS ~27 KB, VGPR 44, occupancy ~47%, no spill.
// bound (256,4): cap 64 > true need 44 — expected codegen-identical to R17's bound-3.
// Spill detector: WRITE_SIZE must stay ~2 MB.
__global__ __launch_bounds__(256, 4) void k2_fft(const float2* __restrict__ Rc,
                                                 const float2* __restrict__ wtab_g,
                                                 float* __restrict__ r_arr,
                                                 int* __restrict__ t_arr) {
  // XCD-aware bijective swizzle (T1): grid = 9216 = 8 * 1152 -> each XCD gets 2 contiguous batches.
  const int phys = blockIdx.x;
  int idx = (phys & 7) * 1152 + (phys >> 3);
  const int b = idx / 576;
  idx -= b * 576;
  int g = 0;
  while (true) { const int cnt = (8 - g) << 4; if (idx < cnt) break; idx -= cnt; ++g; }
  const int rows = 8 - g;
  const int c1 = (g << 4) + idx / rows;
  const int c2t = g + idx % rows;
  const int c2base = c2t << 4;
  const int tid = threadIdx.x;
  const int wid = tid >> 6, lane = tid & 63;

  __shared__ float2 r1c[NF];
  __shared__ float2 t9[81];                   // W9^{a*c} at [9a+c]
  __shared__ float2 t45[45];                  // W45^{b*c} at [9b+c]
  __shared__ float2 Yw[4][360];               // per-wave: Z then stage-1 out (in place)
  __shared__ __align__(16) float ccw[4][728]; // per-wave cc row

  for (int f = tid; f < NF; f += 256) r1c[f] = Rc[((size_t)(b * C_ + c1)) * NF + f];
  for (int i = tid; i < 81; i += 256) { int a = i / 9, c = i % 9; t9[i] = wtab_g[80 * ((a * c) % 9)]; }
  for (int i = tid; i < 45; i += 256) { int bb = i / 9, c = i % 9; t45[i] = wtab_g[16 * bb * c]; }
  __syncthreads();                   // the only block-wide barrier

  const float SCALE = 1.0f / 518400.0f;   // 1/720^2

  for (int j = 0; j < 4; ++j) {
    const int c2 = c2base + (wid << 2) + j;
    if (c2 < c1) continue;           // diagonal-tile waste: nothing would be emitted
    const float2* R2 = Rc + ((size_t)(b * C_ + c2)) * NF;   // L2-hot after swizzle

    // ---- stage 1a: Z build -> Yw. Tiny per-task register footprint, coalesced loads.
    for (int k = lane; k < 360; k += 64) {
      const int fB = 360 - k;                  // in [1, 360]
      const float2 a1 = r1c[k];
      const float2 a2 = r1c[fB];
      const float2 b1 = R2[k];
      const float2 b2 = R2[fB];
      const float2 pA = make_float2(a1.x*b1.x + a1.y*b1.y, a1.y*b1.x - a1.x*b1.y);
      float2 pB = make_float2(a2.x*b2.x + a2.y*b2.y, a2.y*b2.x - a2.x*b2.y);
      pB.y = (k == 0) ? pB.y : -pB.y;          // conj for k>=1
      const float2 E = make_float2(pA.x + pB.x, pA.y + pB.y);
      const float2 O = make_float2(pA.x - pB.x, pA.y - pB.y);
      const float2 Ow = cmulp(O, wtab_g[k]);
      Yw[wid][k] = make_float2(E.x - Ow.y, E.y + Ow.x);   // Z = E + i*Ow
    }
    WSYNC();   // Z visible to my wave's 1b

    // ---- stage 1b: in-place DFT-8 over the stride-45 set + exact W360 twiddle.
    if (lane < 45) {
      const int K2 = lane;
      float2 zin[8];
#pragma unroll
      for (int q1 = 0; q1 < 8; ++q1) zin[q1] = Yw[wid][45 * q1 + K2];
      float2 X[8];
      dft8_pos(zin, X);
      int m = 0;                               // m = 2*K2*n1 <= 616: no mod needed
#pragma unroll
      for (int n1 = 0; n1 < 8; ++n1) {
        Yw[wid][n1 * 45 + K2] = cmulp(X[n1], wtab_g[m]);   // exact W360^{K2*n1}
        m += 2 * K2;
      }
    }
    WSYNC();   // my wave's Yw writes visible to my wave's stage-2 reads

    // ---- stage 2: DFT-45 per n1-row (9x5 CT): 72 (row,col) tasks over 64 lanes, 2 fenced passes.
    {
      auto s2_task = [&](int t) {
        const int n1 = t / 9;
        const int c  = t - 9 * n1;
        const float2* Yrow = &Yw[wid][n1 * 45];
        float yr[5], yi[5];
#pragma unroll
        for (int d = 0; d < 5; ++d) { yr[d] = 0.f; yi[d] = 0.f; }
#pragma unroll 1
        for (int bq = 0; bq < 5; ++bq) {
          float ur = 0.f, ui = 0.f;
#pragma unroll
          for (int a = 0; a < 9; ++a) {
            const float2 zv = Yrow[5 * a + bq];   // scalar LDS loads: no z[9] register array
            const float2 tv = t9[9 * a + c];
            ur += zv.x * tv.x - zv.y * tv.y;
            ui += zv.x * tv.y + zv.y * tv.x;
          }
          const float2 tw = t45[9 * bq + c];
          const float vr = ur * tw.x - ui * tw.y;
          const float vi = ur * tw.y + ui * tw.x;
#pragma unroll
          for (int d = 0; d < 5; ++d) {
            const int m = (bq * d) % 5;           // compile-time
            yr[d] += vr * W5X[m] - vi * W5Y[m];
            yi[d] += vr * W5Y[m] + vi * W5X[m];
          }
        }
        float2* cc2 = (float2*)(&ccw[wid][0]);
#pragma unroll
        for (int d = 0; d < 5; ++d)
          cc2[n1 + 8 * (c + 9 * d)] = make_float2(yr[d], yi[d]);   // cc[2n], cc[2n+1]
      };
      s2_task(lane);                           // pass 0: tasks 0..63
      __builtin_amdgcn_sched_barrier(0);       // fence: do NOT interleave pass chains (R11 lesson)
      if (lane < 8) s2_task(64 + lane);        // pass 1: tasks 64..71
      __builtin_amdgcn_sched_barrier(0);
    }
    WSYNC();   // ccw writes visible to my wave's scan

    // ---- merged peak scan (fwd + mirror), full wave, width-64 reduce (R9-verified semantics).
    {
      const float* cr = ccw[wid];
      float bvF = 0.f; int btF = 1;
      float bvM = 0.f; int uM  = 719;      // -> t' = 1 on all-zero
      for (int i = lane; i < 719; i += 64) {
        const int u = i + 1;               // 1..719
        const float v  = fabsf(cr[u]);
        const float lf = fabsf(cr[u - 1]);
        const float rt = fabsf(cr[(u == 719) ? 0 : (u + 1)]);
        if (v >= lf && v >= rt) {
          if (u <= 718 && (v > bvF || (v == bvF && u < btF))) { bvF = v; btF = u; }
          if (u >= 2   && (v > bvM || (v == bvM && u > uM)))  { bvM = v; uM  = u; }
        }
      }
      for (int off = 32; off; off >>= 1) {
        const float ovF = __shfl_down(bvF, off, 64); const int otF = __shfl_down(btF, off, 64);
        if (ovF > bvF || (ovF == bvF && otF < btF)) { bvF = ovF; btF = otF; }
        const float ovM = __shfl_down(bvM, off, 64); const int ouM = __shfl_down(uM, off, 64);
        if (ovM > bvM || (ovM == bvM && ouM > uM)) { bvM = ovM; uM = ouM; }
      }
      if (lane == 0) {
        const float rF = (bvF > 0.f) ? cr[btF] * SCALE : 0.f;
        const size_t o = ((size_t)(b * C_ + c1)) * C_ + c2;
        r_arr[o] = rF; t_arr[o] = btF;
        if (c2 > c1) {
          const float rM = (bvM > 0.f) ? cr[uM] * SCALE : 0.f;
          const size_t o2 = ((size_t)(b * C_ + c2)) * C_ + c1;
          r_arr[o2] = rM; t_arr[o2] = 720 - uM;
        }
      }
    }
    WSYNC();   // scan's ccw reads done before next j overwrites
  }
}

// ---------------------------------------------------------------- K34: leaders/softmax/filt + spectral mix + output (fused; filt/leads stay in LDS)
__global__ __launch_bounds__(256) void k34_fused(const float* __restrict__ x,
                                                 const float* __restrict__ temperature,
                                                 const float* __restrict__ cls_w,
                                                 const float* __restrict__ basic_state,
                                                 const float* __restrict__ state_bias,
                                                 const float* __restrict__ mhw,
                                                 const float* __restrict__ mhb,
                                                 const float* __restrict__ r_arr,
                                                 const int* __restrict__ t_arr,
                                                 const float* __restrict__ seq,
                                                 const float* __restrict__ mu_g,
                                                 const float* __restrict__ std_g,
                                                 const float* __restrict__ mwr,
                                                 const float* __restrict__ mwi,
                                                 const float* __restrict__ mbr,
                                                 const float* __restrict__ mbi,
                                                 float* __restrict__ out) {
  const int bc = blockIdx.x;
  const int b = bc >> 7, c = bc & 127;
  const int tid = threadIdx.x;
  __shared__ float caL[C_], rL[C_];
  __shared__ int tL[C_];
  __shared__ float xrowL[L_];
  __shared__ float cfL[K_], srL[K_], pL[S_], qL[S_ * K_], praw[S_];
  __shared__ int leadL[K_], ltL[K_];
  __shared__ float cosT[96], sinT[96];
  __shared__ float ssL[K_][H_], ynL[H_], flL[OUT_];
  __shared__ float sfr[K_][F2_], sfi[K_][F2_], yfr[F2_], yfi[F2_];
  __shared__ float catr[3 * F2_], cati[3 * F2_], ofr[F2_], ofi[F2_];

  // ---- gather inputs (k3 part + k4 tables)
  const float* xb = x + (size_t)b * L_ * C_ + c;
  for (int l = tid; l < L_; l += 256) xrowL[l] = xb[(size_t)l * C_];
  if (tid < C_) {
    const float r = r_arr[(size_t)bc * C_ + tid];
    rL[tid] = r; caL[tid] = fabsf(r);
    tL[tid] = t_arr[(size_t)bc * C_ + tid];
  }
  if (tid >= 128 && tid < 224) {
    const int h = tid - 128;
    const float ang = (float)h * (float)(6.283185307179586 / 96.0);
    cosT[h] = cosf(ang); sinT[h] = sinf(ang);
    ynL[h] = seq[(size_t)bc * SEQLEN + L_ + h];
  }
  __syncthreads();

  // ---- top-k leaders + corr softmax (serial, tiny)
  if (tid == 0) {
    const float T = temperature[0];
    float lg[K_ + 1];
    lg[0] = 1.0f / T;
    for (int k = 0; k < K_; ++k) {       // stable top-k: strict > keeps smallest index on ties
      float bvv = -1.f; int bi = 0;
      for (int jj = 0; jj < C_; ++jj) { const float v = caL[jj]; if (v > bvv) { bvv = v; bi = jj; } }
      leadL[k] = bi; ltL[k] = tL[bi];
      const float rv = rL[bi];
      srL[k] = (rv > 0.f) ? 1.f : ((rv < 0.f) ? -1.f : 0.f);
      lg[k + 1] = bvv / T;
      caL[bi] = -2.f;
    }
    float m = lg[0];
    for (int k = 1; k <= K_; ++k) m = fmaxf(m, lg[k]);
    float sum = 0.f, e[K_ + 1];
    for (int k = 0; k <= K_; ++k) { e[k] = expf(lg[k] - m); sum += e[k]; }
    const float invs = 1.0f / sum;
    for (int k = 0; k < K_; ++k) cfL[k] = e[k + 1] * invs;
  }

  // ---- p logits: 8 groups of 32 lanes
  {
    const int gg = tid >> 5, lane = tid & 31;
    float acc = 0.f;
    const float* w = cls_w + (size_t)gg * L_;
    for (int l = lane; l < L_; l += 32) acc += xrowL[l] * w[l];
    for (int off = 16; off; off >>= 1) acc += __shfl_down(acc, off, 32);
    if (lane == 0) praw[gg] = acc + state_bias[gg] + basic_state[c * S_ + gg];
  }
  __syncthreads();
  if (tid == 0) {
    float m = praw[0];
    for (int s2 = 1; s2 < S_; ++s2) m = fmaxf(m, praw[s2]);
    float sum = 0.f;
    for (int s2 = 0; s2 < S_; ++s2) { const float e = expf(praw[s2] - m); pL[s2] = e; sum += e; }
    const float invs = 1.0f / sum;
    for (int s2 = 0; s2 < S_; ++s2) pL[s2] *= invs;
    for (int s2 = 0; s2 < S_; ++s2)
      for (int k = 0; k < K_; ++k) qL[s2 * K_ + k] = pL[s2] * cfL[k];
  }
  __syncthreads();

  // ---- filt -> LDS; leader window gather (both depend on step above)
  for (int o = tid; o < OUT_; o += 256) {
    float acc = 0.f;
#pragma unroll
    for (int s2 = 0; s2 < S_; ++s2) {
      acc += pL[s2] * mhb[s2 * OUT_ + o];
#pragma unroll
      for (int k = 0; k < K_; ++k)
        acc += qL[s2 * K_ + k] * mhw[(size_t)s2 * (K_ * OUT_) + k * OUT_ + o];
    }
    flL[o] = acc;
  }
  for (int i = tid; i < K_ * H_; i += 256) {
    const int k = i / H_, h = i - k * H_;
    ssL[k][h] = seq[((size_t)(b * C_ + leadL[k])) * SEQLEN + (L_ + h - ltL[k])] * srL[k];
  }
  __syncthreads();

  // ---- 96-pt rfft (DFT) of ss rows and yn
  for (int u = tid; u < K_ * F2_ + F2_; u += 256) {
    if (u < K_ * F2_) {
      const int k = u / F2_, f = u - k * F2_;
      float re = 0.f, im = 0.f; int m = 0;
      for (int h = 0; h < H_; ++h) {
        const float v = ssL[k][h];
        re = fmaf(v, cosT[m], re); im = fmaf(-v, sinT[m], im);
        m += f; if (m >= 96) m -= 96;
      }
      sfr[k][f] = re; sfi[k][f] = im;
    } else {
      const int f = u - K_ * F2_;
      float re = 0.f, im = 0.f; int m = 0;
      for (int h = 0; h < H_; ++h) {
        const float v = ynL[h];
        re = fmaf(v, cosT[m], re); im = fmaf(-v, sinT[m], im);
        m += f; if (m >= 96) m -= 96;
      }
      yfr[f] = re; yfi[f] = im;
    }
  }
  __syncthreads();

  if (tid < F2_) {
    const int f = tid;
    float s1r = 0.f, s1i = 0.f, s2r = 0.f, s2i = 0.f;
    const float yr = yfr[f], yi = yfi[f];
#pragma unroll
    for (int k = 0; k < K_; ++k) {
      const float fa = flL[k * F2_ + f], fb = flL[(K_ + k) * F2_ + f];
      const float ar = sfr[k][f] * fa, ai = sfi[k][f] * fa;
      s1r += ar; s1i += ai;
      s2r += (ar - yr) * fb; s2i += (ai - yi) * fb;
    }
    const float fc = flL[2 * K_ * F2_ + f];
    catr[f] = s1r;            cati[f] = s1i;
    catr[F2_ + f] = s2r;      cati[F2_ + f] = s2i;
    catr[2 * F2_ + f] = yr * fc; cati[2 * F2_ + f] = yi * fc;
  }
  __syncthreads();

  if (tid < F2_) {
    const int o = tid;
    float ar = mbr[o], ai = mbi[o];
    const float* wr = mwr + (size_t)o * (3 * F2_);
    const float* wi = mwi + (size_t)o * (3 * F2_);
    for (int f = 0; f < 3 * F2_; ++f) {
      const float cr = catr[f], ci = cati[f];
      const float wrr = wr[f], wii = wi[f];
      ar += cr * wrr - ci * wii;
      ai += cr * wii + ci * wrr;
    }
    ofr[o] = ar; ofi[o] = ai;
  }
  __syncthreads();

  if (tid < H_) {
    const int h = tid;
    float val = ofr[0] + ofr[48] * ((h & 1) ? -1.f : 1.f);
    int m = h;                                  // (f*h)%96 for f=1
    for (int f = 1; f < 48; ++f) {
      val += 2.f * (ofr[f] * cosT[m] - ofi[f] * sinT[m]);
      m += h; if (m >= 96) m -= 96;
    }
    val *= (1.0f / 96.0f);
    const float mu = mu_g[bc], stdv = std_g[bc];
    out[((size_t)b * H_ + h) * C_ + c] = (ynL[h] + val) * stdv + mu;
  }
}

// ---------------------------------------------------------------- launch
extern "C" void kernel_launch(void* const* d_in, const int* in_sizes, int n_in,
                              void* d_out, int out_size, void* d_ws, size_t ws_size,
                              hipStream_t stream) {
  const float* x    = (const float*)d_in[0];
  const float* yh   = (const float*)d_in[1];
  const float* temp = (const float*)d_in[2];
  const float* clsw = (const float*)d_in[3];
  const float* bst  = (const float*)d_in[4];
  const float* sbias= (const float*)d_in[5];
  const float* mhw  = (const float*)d_in[6];
  const float* mhb  = (const float*)d_in[7];
  const float* mwr  = (const float*)d_in[8];
  const float* mwi  = (const float*)d_in[9];
  const float* mbr  = (const float*)d_in[10];
  const float* mbi  = (const float*)d_in[11];
  float* out = (float*)d_out;

  float* ws = (float*)d_ws;
  float* seq    = ws;                                   // 2048*816
  float* mu_g   = seq + (size_t)2048 * SEQLEN;          // 2048
  float* std_g  = mu_g + 2048;                          // 2048
  float* r_arr  = std_g + 2048;                         // 262144
  int*   t_arr  = (int*)(r_arr + (size_t)2048 * C_);    // 262144
  float2* Rc    = (float2*)(t_arr + (size_t)2048 * C_); // 2048*361 float2
  float2* wtab  = Rc + (size_t)2048 * NF;               // 720 float2

  hipLaunchKernelGGL(k0_tab, dim3(1), dim3(256), 0, stream, wtab);
  hipLaunchKernelGGL(k1_fused, dim3(B_ * C_ / 2), dim3(256), 0, stream, x, yh, wtab, seq, mu_g, std_g, Rc);
  hipLaunchKernelGGL(k2_fft, dim3(B_ * 576), dim3(256), 0, stream, Rc, wtab, r_arr, t_arr);
  hipLaunchKernelGGL(k34_fused, dim3(B_ * C_), dim3(256), 0, stream,
                     x, temp, clsw, bst, sbias, mhw, mhb, r_arr, t_arr,
                     seq, mu_g, std_g, mwr, mwi, mbr, mbi, out);
}